// Round 20
// baseline (61.955 us; speedup 1.0000x reference)
//
#include <hip/hip_runtime.h>
#include <hip/hip_bf16.h>

typedef float  f32x4  __attribute__((ext_vector_type(4)));
typedef short  s16x8  __attribute__((ext_vector_type(8)));
typedef __bf16 bf16x8 __attribute__((ext_vector_type(8)));
typedef unsigned int u32x4 __attribute__((ext_vector_type(4)));

namespace {
constexpr int BHW = 16384, L = 8, K = 512, D = 16, HW = 1024, CH = 128;
constexpr int TPB = 512;   // 8 waves; wave = 32 pixels x all 512 codes
constexpr int PPB = 256;   // grid = 512 blocks = 2/CU
constexpr float KAPPA = 2.0813689810056077f;    // (log2 e)^2
constexpr size_t WS_CA_BYTES = (size_t)L * K * 32 * 2;          // 262144
constexpr size_t WS_W2_BYTES = (size_t)L * K * 4;               // 16384
constexpr size_t WS_W2K_OFF  = WS_CA_BYTES + WS_W2_BYTES;       // 278528

__device__ __forceinline__ f32x4 mfma16(s16x8 a, s16x8 b, f32x4 c) {
  return __builtin_amdgcn_mfma_f32_16x16x32_bf16(
      __builtin_bit_cast(bf16x8, a), __builtin_bit_cast(bf16x8, b), c, 0, 0, 0);
}
__device__ __forceinline__ unsigned short bfh(float x) {
  return __builtin_bit_cast(unsigned short, __float2bfloat16(x));
}
__device__ __forceinline__ float bf2f(unsigned short u) {
  return __bfloat162float(__builtin_bit_cast(__hip_bfloat16, u));
}
__device__ __forceinline__ unsigned cvtpk(float lo, float hi) {
  unsigned r;
  asm("v_cvt_pk_bf16_f32 %0, %1, %2" : "=v"(r) : "v"(lo), "v"(hi));
  return r;
}

__global__ void repack(const float* __restrict__ codes,
                       unsigned short* __restrict__ cA,
                       float* __restrict__ w2g, float* __restrict__ w2k) {
  int i = blockIdx.x * 256 + threadIdx.x;          // (l,k)
  const float* c = codes + (size_t)i * D;
  float s = 0.f;
  #pragma unroll
  for (int d = 0; d < D; ++d) s = fmaf(c[d], c[d], s);   // rounding-contract chain
  w2g[i] = s;                // exact (rescan path)
  w2k[i] = KAPPA * s;        // scaled (main-loop path)
  int l = i >> 9, k = i & (K - 1);
  int ck = k >> 5, kloc = k & 31, g = kloc >> 3, w = kloc & 7, t = w >> 2, r = w & 3;
  int prow = ck * 32 + t * 16 + g * 4 + r;         // permuted A row for code k
  unsigned short* dst = cA + ((size_t)l * K + prow) * 32;
  #pragma unroll
  for (int d = 0; d < D; ++d) {
    unsigned short hi = bfh(c[d]);
    dst[d] = hi; dst[16 + d] = bfh(c[d] - bf2f(hi));
  }
}

__global__ __launch_bounds__(TPB, 4) void enc_mfma(
    const float* __restrict__ z,
    const float* __restrict__ codes,
    const unsigned short* __restrict__ cA,
    const float* __restrict__ w2g,     // exact
    const float* __restrict__ w2k,     // scaled by KAPPA
    float* __restrict__ out)
{
  __shared__ short cB[2][8192];     // 32 KB; first reused as hstg f32 [256][17]
  __shared__ short cAl[16384];      // 32 KB: A-slice LDS-resident
  __shared__ float w2s[K];
  __shared__ float h2s[PPB];
  __shared__ float ssum[8][32];
  __shared__ int   bks[8][32];

  const int tid  = threadIdx.x;
  const int l    = blockIdx.y;
  const int bx   = blockIdx.x;
  const int bimg = bx >> 2;
  const int yx0  = (bx & 3) * PPB;

  float* hstg = (float*)&cB[0][0];  // [256][17]
  {
    const int i = tid & 255, dc = tid >> 8;
    #pragma unroll
    for (int it = 0; it < 8; ++it) {
      int d = dc * 8 + it;
      hstg[i * 17 + d] = z[((size_t)(bimg * CH + l * D + d)) * HW + yx0 + i];
    }
  }
  {
    const s16x8* src = (const s16x8*)(cA + ((size_t)l * K + tid) * 32);
    s16x8* dst = (s16x8*)cAl + tid * 4;
    dst[0] = src[0]; dst[1] = src[1]; dst[2] = src[2]; dst[3] = src[3];
  }
  __syncthreads();

  const int wv   = __builtin_amdgcn_readfirstlane(tid >> 6);
  const int lane = tid & 63;
  const int cl   = lane & 15;
  const int g    = lane >> 4;
  const int pw   = wv * 32;

  if (tid < PPB) {
    float h2 = 0.f;
    #pragma unroll
    for (int d = 0; d < 16; ++d) { float v = hstg[tid * 17 + d]; h2 = fmaf(v, v, h2); }
    h2s[tid] = h2;                  // exact chain (rescan + scaled local)
  }
  s16x8 B1a, B2a, B1b, B2b;
  {
    const int off = (g & 1) * 8;
    #pragma unroll
    for (int j = 0; j < 8; ++j) {
      float va = hstg[(pw + cl) * 17 + off + j];
      unsigned short ha = bfh(va);
      B1a[j] = (short)ha; B2a[j] = (short)bfh(va - bf2f(ha));
      float vb = hstg[(pw + 16 + cl) * 17 + off + j];
      unsigned short hb = bfh(vb);
      B1b[j] = (short)hb; B2b[j] = (short)bfh(vb - bf2f(hb));
    }
  }
  __syncthreads();
  const float h2ka = KAPPA * h2s[pw + cl];
  const float h2kb = KAPPA * h2s[pw + 16 + cl];

  {
    int k = tid, ck = k >> 5, kloc = k & 31, gg = kloc >> 3, w = kloc & 7, t = w >> 2, r = w & 3;
    int prow = ck * 32 + t * 16 + gg * 4 + r;
    const s16x8* src = (const s16x8*)(cA + ((size_t)l * K + prow) * 32);
    s16x8 h0 = src[0], h1 = src[1], l0 = src[2], l1 = src[3];
    int base = (ck * 4 + gg) * 128 + w;
    #pragma unroll
    for (int d = 0; d < 8; ++d) {
      cB[0][base + d * 8]       = h0[d];
      cB[1][base + d * 8]       = l0[d];
      cB[0][base + (d + 8) * 8] = h1[d];
      cB[1][base + (d + 8) * 8] = l1[d];
    }
    w2s[k] = w2k[l * K + k];
  }
  __syncthreads();

  const s16x8* Abl = (const s16x8*)cAl + (cl * 4 + g);   // conflict-free bijection
  const s16x8 ONES = {(short)0x3F80, (short)0x3F80, (short)0x3F80, (short)0x3F80,
                      (short)0x3F80, (short)0x3F80, (short)0x3F80, (short)0x3F80};

  float m2A = 1e30f, mbA = 1e30f;
  float m2B = 1e30f, mbB = 1e30f;
  f32x4 pva0 = {0,0,0,0}, pva1 = {0,0,0,0}, pvsA = {0,0,0,0};
  f32x4 pvb0 = {0,0,0,0}, pvb1 = {0,0,0,0}, pvsB = {0,0,0,0};

  auto soft8 = [&](const f32x4& T0, const f32x4& T1, const f32x4& W0, const f32x4& W1,
                   float h2k, int ct, float& m2, float& m2b) -> s16x8 {
    float wv_[8];
    #pragma unroll
    for (int t = 0; t < 2; ++t) {
      #pragma unroll
      for (int r = 0; r < 4; ++r) {
        float T  = t ? T1[r] : T0[r];
        float Wk = t ? W1[r] : W0[r];
        float d2 = fmaf(-2.f * KAPPA, T, h2k) + Wk;   // scaled d2 (order-preserving)
        int kloc = ct * 32 + 8 * g + t * 4 + r;
        // raw d2 key (no clamp): tiny-negative d2 sorts first -> trigger fires -> rescan fixes
        float key = __int_as_float((__float_as_int(d2) & 0xFFFFFE00) | kloc);
        m2b = __builtin_amdgcn_fmed3f(key, m2, m2b);
        m2  = fminf(m2, key);
        float dist = __builtin_amdgcn_sqrtf(__builtin_fabsf(d2));  // abs = free modifier
        wv_[t * 4 + r] = __builtin_amdgcn_exp2f(-dist);            // = exp(-true dist)
      }
    }
    u32x4 uu;
    uu[0] = cvtpk(wv_[0], wv_[1]);
    uu[1] = cvtpk(wv_[2], wv_[3]);
    uu[2] = cvtpk(wv_[4], wv_[5]);
    uu[3] = cvtpk(wv_[6], wv_[7]);
    return __builtin_bit_cast(s16x8, uu);
  };

  // ---- 1-deep T software pipeline, enforced by sched_barrier(0) fences ----
  f32x4 T0a_p = {0,0,0,0}, T1a_p = {0,0,0,0}, T0b_p = {0,0,0,0}, T1b_p = {0,0,0,0};
  {
    s16x8 A0 = Abl[0], A1 = Abl[64];
    __builtin_amdgcn_s_setprio(1);
    T0a_p = mfma16(A0, B1a, T0a_p); T0a_p = mfma16(A0, B2a, T0a_p);
    T1a_p = mfma16(A1, B1a, T1a_p); T1a_p = mfma16(A1, B2a, T1a_p);
    T0b_p = mfma16(A0, B1b, T0b_p); T0b_p = mfma16(A0, B2b, T0b_p);
    T1b_p = mfma16(A1, B1b, T1b_p); T1b_p = mfma16(A1, B2b, T1b_p);
    __builtin_amdgcn_s_setprio(0);
  }

  #pragma unroll 2
  for (int ct = 0; ct < 16; ++ct) {
    // phase A: issue QK(ct+1) — results consumed NEXT iteration
    f32x4 T0a_c = {0,0,0,0}, T1a_c = {0,0,0,0}, T0b_c = {0,0,0,0}, T1b_c = {0,0,0,0};
    if (ct < 15) {
      s16x8 A0 = Abl[(ct + 1) * 128], A1 = Abl[(ct + 1) * 128 + 64];
      __builtin_amdgcn_s_setprio(1);
      T0a_c = mfma16(A0, B1a, T0a_c); T0a_c = mfma16(A0, B2a, T0a_c);
      T1a_c = mfma16(A1, B1a, T1a_c); T1a_c = mfma16(A1, B2a, T1a_c);
      T0b_c = mfma16(A0, B1b, T0b_c); T0b_c = mfma16(A0, B2b, T0b_c);
      T1b_c = mfma16(A1, B1b, T1b_c); T1b_c = mfma16(A1, B2b, T1b_c);
      __builtin_amdgcn_s_setprio(0);
    }
    __builtin_amdgcn_sched_barrier(0);   // QK(ct+1) pinned BEFORE tail(ct)

    s16x8 Bh = *(const s16x8*)&cB[0][(ct * 4 + g) * 128 + cl * 8];
    s16x8 Bl = *(const s16x8*)&cB[1][(ct * 4 + g) * 128 + cl * 8];
    f32x4 W0 = *(const f32x4*)&w2s[ct * 32 + 8 * g];
    f32x4 W1 = *(const f32x4*)&w2s[ct * 32 + 8 * g + 4];

    s16x8 PAa = soft8(T0a_p, T1a_p, W0, W1, h2ka, ct, m2A, mbA);
    s16x8 PAb = soft8(T0b_p, T1b_p, W0, W1, h2kb, ct, m2B, mbB);
    __builtin_amdgcn_s_setprio(1);
    pva0 = mfma16(PAa, Bh, pva0); pva1 = mfma16(PAa, Bl, pva1); pvsA = mfma16(PAa, ONES, pvsA);
    pvb0 = mfma16(PAb, Bh, pvb0); pvb1 = mfma16(PAb, Bl, pvb1); pvsB = mfma16(PAb, ONES, pvsB);
    __builtin_amdgcn_s_setprio(0);
    __builtin_amdgcn_sched_barrier(0);   // tail/PV(ct) stays before rotation

    T0a_p = T0a_c; T1a_p = T1a_c; T0b_p = T0b_c; T1b_p = T1b_c;
  }
  f32x4 pva = pva0 + pva1;
  f32x4 pvb = pvb0 + pvb1;

  // ---- reduce (min, 2nd-min) over the 4 lane-groups sharing each pixel ----
  #pragma unroll
  for (int off = 16; off < 64; off <<= 1) {
    float mo = __shfl_xor(m2A, off), mbo = __shfl_xor(mbA, off);
    mbA = fminf(fminf(mbA, mbo), fmaxf(m2A, mo));
    m2A = fminf(m2A, mo);
    float mo2 = __shfl_xor(m2B, off), mbo2 = __shfl_xor(mbB, off);
    mbB = fminf(fminf(mbB, mbo2), fmaxf(m2B, mo2));
    m2B = fminf(m2B, mo2);
  }
  int kaA = __float_as_int(m2A) & 511;
  int kaB = __float_as_int(m2B) & 511;
  bool trigA = (__int_as_float(__float_as_int(mbA) & 0xFFFFFE00) -
                __int_as_float(__float_as_int(m2A) & 0xFFFFFE00)) < 0.045f;  // 0.02*KAPPA + margin
  bool trigB = (__int_as_float(__float_as_int(mbB) & 0xFFFFFE00) -
                __int_as_float(__float_as_int(m2B) & 0xFFFFFE00)) < 0.045f;

  if (cl == 0) {
    #pragma unroll
    for (int r = 0; r < 4; ++r) {
      ssum[wv][g * 4 + r]      = pvsA[r];
      ssum[wv][16 + g * 4 + r] = pvsB[r];
    }
  }
  if (lane < 16) { bks[wv][lane] = kaA; bks[wv][16 + lane] = kaB; }

  // ---- rare exact rescan (np-exact chain + precise sqrt, first occurrence) ----
  unsigned long long mask = __ballot(lane < 16 && trigA) |
                            (__ballot(lane < 16 && trigB) << 16);
  while (mask) {
    int pl = __ffsll((long long)mask) - 1; mask &= mask - 1;
    float hh[16];
    #pragma unroll
    for (int d = 0; d < 16; ++d)
      hh[d] = z[((size_t)(bimg * CH + l * D + d)) * HW + yx0 + pw + pl];
    float h2x = h2s[pw + pl];
    float bm = 1e30f; int bkk = 0;
    for (int rnd = 0; rnd < 8; ++rnd) {
      int k = rnd * 64 + lane;
      const float* cr = codes + ((size_t)l * K + k) * D;
      float cross = 0.f;
      #pragma unroll
      for (int d = 0; d < 16; ++d) cross = fmaf(hh[d], cr[d], cross);
      float d2 = (h2x - 2.f * cross) + w2g[l * K + k];
      d2 = fmaxf(d2, 1e-12f);
      float dist = sqrtf(d2);
      if (dist < bm) { bm = dist; bkk = k; }
    }
    #pragma unroll
    for (int off = 1; off < 64; off <<= 1) {
      float bo = __shfl_xor(bm, off); int ko = __shfl_xor(bkk, off);
      if (bo < bm || (bo == bm && ko < bkk)) { bm = bo; bkk = ko; }
    }
    if (lane == 0) bks[wv][pl] = bkk;
  }

  // ---- epilogue ----
  __syncthreads();
  const int pg0 = bimg * HW + yx0;
  f32x4 svA = *(const f32x4*)&ssum[wv][g * 4];
  f32x4 svB = *(const f32x4*)&ssum[wv][16 + g * 4];
  #pragma unroll
  for (int r = 0; r < 4; ++r) {
    out[(size_t)(pg0 + pw + g * 4 + r) * CH + l * D + cl]      = pva[r] * __builtin_amdgcn_rcpf(svA[r]);
    out[(size_t)(pg0 + pw + 16 + g * 4 + r) * CH + l * D + cl] = pvb[r] * __builtin_amdgcn_rcpf(svB[r]);
  }
  int kkA = bks[wv][cl];
  int kkB = bks[wv][16 + cl];
  float4 cvA = *(const float4*)&codes[((size_t)l * K + kkA) * D + g * 4];
  float4 cvB = *(const float4*)&codes[((size_t)l * K + kkB) * D + g * 4];
  *(float4*)&out[(size_t)BHW * CH + (size_t)(pg0 + pw + cl) * CH + l * D + g * 4]      = cvA;
  *(float4*)&out[(size_t)BHW * CH + (size_t)(pg0 + pw + 16 + cl) * CH + l * D + g * 4] = cvB;
  if (lane < 16) {
    out[(size_t)2 * BHW * CH + (size_t)(pg0 + pw + cl) * L + l]      = (float)kkA;
    out[(size_t)2 * BHW * CH + (size_t)(pg0 + pw + 16 + cl) * L + l] = (float)kkB;
  }
}
} // namespace

extern "C" void kernel_launch(void* const* d_in, const int* in_sizes, int n_in,
                              void* d_out, int out_size, void* d_ws, size_t ws_size,
                              hipStream_t stream) {
  const float* z     = (const float*)d_in[0];
  const float* codes = (const float*)d_in[1];
  float* out         = (float*)d_out;
  unsigned short* cA = (unsigned short*)d_ws;
  float* w2g         = (float*)((char*)d_ws + WS_CA_BYTES);
  float* w2k         = (float*)((char*)d_ws + WS_W2K_OFF);

  repack<<<dim3(L * K / 256), 256, 0, stream>>>(codes, cA, w2g, w2k);
  dim3 grid(BHW / PPB, L);
  enc_mfma<<<grid, TPB, 0, stream>>>(z, codes, cA, w2g, w2k, out);
}

// Round 21
// 58.642 us; speedup vs baseline: 1.0565x; 1.0565x over previous
//
#include <hip/hip_runtime.h>
#include <hip/hip_bf16.h>

typedef float  f32x4  __attribute__((ext_vector_type(4)));
typedef short  s16x8  __attribute__((ext_vector_type(8)));
typedef __bf16 bf16x8 __attribute__((ext_vector_type(8)));
typedef unsigned int u32x4 __attribute__((ext_vector_type(4)));

namespace {
constexpr int BHW = 16384, L = 8, K = 512, D = 16, HW = 1024, CH = 128;
constexpr int TPB = 512;   // 8 waves; wave = 32 pixels x all 512 codes
constexpr int PPB = 256;   // grid = 512 blocks = 2/CU
constexpr float KAPPA = 2.0813689810056077f;    // (log2 e)^2
constexpr size_t WS_CA_BYTES = (size_t)L * K * 32 * 2;          // 262144
constexpr size_t WS_W2_BYTES = (size_t)L * K * 4;               // 16384
constexpr size_t WS_W2K_OFF  = WS_CA_BYTES + WS_W2_BYTES;       // 278528

__device__ __forceinline__ f32x4 mfma16(s16x8 a, s16x8 b, f32x4 c) {
  return __builtin_amdgcn_mfma_f32_16x16x32_bf16(
      __builtin_bit_cast(bf16x8, a), __builtin_bit_cast(bf16x8, b), c, 0, 0, 0);
}
__device__ __forceinline__ unsigned short bfh(float x) {
  return __builtin_bit_cast(unsigned short, __float2bfloat16(x));
}
__device__ __forceinline__ float bf2f(unsigned short u) {
  return __bfloat162float(__builtin_bit_cast(__hip_bfloat16, u));
}
__device__ __forceinline__ unsigned cvtpk(float lo, float hi) {
  unsigned r;
  asm("v_cvt_pk_bf16_f32 %0, %1, %2" : "=v"(r) : "v"(lo), "v"(hi));
  return r;
}

__global__ void repack(const float* __restrict__ codes,
                       unsigned short* __restrict__ cA,
                       float* __restrict__ w2g, float* __restrict__ w2k) {
  int i = blockIdx.x * 256 + threadIdx.x;          // (l,k)
  const float* c = codes + (size_t)i * D;
  float s = 0.f;
  #pragma unroll
  for (int d = 0; d < D; ++d) s = fmaf(c[d], c[d], s);   // rounding-contract chain
  w2g[i] = s;                // exact (rescan path)
  w2k[i] = KAPPA * s;        // scaled (main-loop path)
  int l = i >> 9, k = i & (K - 1);
  int ck = k >> 5, kloc = k & 31, g = kloc >> 3, w = kloc & 7, t = w >> 2, r = w & 3;
  int prow = ck * 32 + t * 16 + g * 4 + r;         // permuted A row for code k
  unsigned short* dst = cA + ((size_t)l * K + prow) * 32;
  #pragma unroll
  for (int d = 0; d < D; ++d) {
    unsigned short hi = bfh(c[d]);
    dst[d] = hi; dst[16 + d] = bfh(c[d] - bf2f(hi));
  }
}

__global__ __launch_bounds__(TPB, 4) void enc_mfma(
    const float* __restrict__ z,
    const float* __restrict__ codes,
    const unsigned short* __restrict__ cA,
    const float* __restrict__ w2g,     // exact
    const float* __restrict__ w2k,     // scaled by KAPPA
    float* __restrict__ out)
{
  __shared__ short cB[2][8192];     // 32 KB; first reused as hstg f32 [256][17]
  __shared__ short cAl[16384];      // 32 KB: A-slice LDS-resident
  __shared__ float w2s[K];
  __shared__ float h2s[PPB];
  __shared__ float ssum[8][32];
  __shared__ int   bks[8][32];

  const int tid  = threadIdx.x;
  const int l    = blockIdx.y;
  const int bx   = blockIdx.x;
  const int bimg = bx >> 2;
  const int yx0  = (bx & 3) * PPB;

  float* hstg = (float*)&cB[0][0];  // [256][17]
  {
    const int i = tid & 255, dc = tid >> 8;
    #pragma unroll
    for (int it = 0; it < 8; ++it) {
      int d = dc * 8 + it;
      hstg[i * 17 + d] = z[((size_t)(bimg * CH + l * D + d)) * HW + yx0 + i];
    }
  }
  {
    const s16x8* src = (const s16x8*)(cA + ((size_t)l * K + tid) * 32);
    s16x8* dst = (s16x8*)cAl + tid * 4;
    dst[0] = src[0]; dst[1] = src[1]; dst[2] = src[2]; dst[3] = src[3];
  }
  __syncthreads();

  const int wv   = __builtin_amdgcn_readfirstlane(tid >> 6);
  const int lane = tid & 63;
  const int cl   = lane & 15;
  const int g    = lane >> 4;
  const int pw   = wv * 32;

  if (tid < PPB) {
    float h2 = 0.f;
    #pragma unroll
    for (int d = 0; d < 16; ++d) { float v = hstg[tid * 17 + d]; h2 = fmaf(v, v, h2); }
    h2s[tid] = h2;                  // exact chain (rescan + scaled local)
  }
  s16x8 B1a, B2a, B1b, B2b;
  {
    const int off = (g & 1) * 8;
    #pragma unroll
    for (int j = 0; j < 8; ++j) {
      float va = hstg[(pw + cl) * 17 + off + j];
      unsigned short ha = bfh(va);
      B1a[j] = (short)ha; B2a[j] = (short)bfh(va - bf2f(ha));
      float vb = hstg[(pw + 16 + cl) * 17 + off + j];
      unsigned short hb = bfh(vb);
      B1b[j] = (short)hb; B2b[j] = (short)bfh(vb - bf2f(hb));
    }
  }
  __syncthreads();
  const float h2ka = KAPPA * h2s[pw + cl];
  const float h2kb = KAPPA * h2s[pw + 16 + cl];

  {
    int k = tid, ck = k >> 5, kloc = k & 31, gg = kloc >> 3, w = kloc & 7, t = w >> 2, r = w & 3;
    int prow = ck * 32 + t * 16 + gg * 4 + r;
    const s16x8* src = (const s16x8*)(cA + ((size_t)l * K + prow) * 32);
    s16x8 h0 = src[0], h1 = src[1], l0 = src[2], l1 = src[3];
    int base = (ck * 4 + gg) * 128 + w;
    #pragma unroll
    for (int d = 0; d < 8; ++d) {
      cB[0][base + d * 8]       = h0[d];
      cB[1][base + d * 8]       = l0[d];
      cB[0][base + (d + 8) * 8] = h1[d];
      cB[1][base + (d + 8) * 8] = l1[d];
    }
    w2s[k] = w2k[l * K + k];
  }
  __syncthreads();

  const s16x8* Abl = (const s16x8*)cAl + (cl * 4 + g);   // conflict-free bijection
  const s16x8 ONES = {(short)0x3F80, (short)0x3F80, (short)0x3F80, (short)0x3F80,
                      (short)0x3F80, (short)0x3F80, (short)0x3F80, (short)0x3F80};

  float m2A = 1e30f, mbA = 1e30f;
  float m2B = 1e30f, mbB = 1e30f;
  f32x4 pva0 = {0,0,0,0}, pva1 = {0,0,0,0}, pvsA = {0,0,0,0};
  f32x4 pvb0 = {0,0,0,0}, pvb1 = {0,0,0,0}, pvsB = {0,0,0,0};

  auto soft8 = [&](const f32x4& T0, const f32x4& T1, const f32x4& W0, const f32x4& W1,
                   float h2k, int ct, float& m2, float& m2b) -> s16x8 {
    float wv_[8];
    #pragma unroll
    for (int t = 0; t < 2; ++t) {
      #pragma unroll
      for (int r = 0; r < 4; ++r) {
        float T  = t ? T1[r] : T0[r];
        float Wk = t ? W1[r] : W0[r];
        float d2 = fmaf(-2.f * KAPPA, T, h2k) + Wk;   // scaled d2 (order-preserving)
        int kloc = ct * 32 + 8 * g + t * 4 + r;
        // raw d2 key (no clamp): tiny-negative d2 sorts first -> trigger fires -> rescan fixes
        float key = __int_as_float((__float_as_int(d2) & 0xFFFFFE00) | kloc);
        m2b = __builtin_amdgcn_fmed3f(key, m2, m2b);
        m2  = fminf(m2, key);
        float dist = __builtin_amdgcn_sqrtf(__builtin_fabsf(d2));  // abs = free modifier
        wv_[t * 4 + r] = __builtin_amdgcn_exp2f(-dist);            // = exp(-true dist)
      }
    }
    // HW pair conversion: 4 ops replace 16 cvt + 16 inserts
    u32x4 uu;
    uu[0] = cvtpk(wv_[0], wv_[1]);
    uu[1] = cvtpk(wv_[2], wv_[3]);
    uu[2] = cvtpk(wv_[4], wv_[5]);
    uu[3] = cvtpk(wv_[6], wv_[7]);
    return __builtin_bit_cast(s16x8, uu);
  };

  #pragma unroll 2
  for (int ct = 0; ct < 16; ++ct) {
    s16x8 A0 = Abl[ct * 128];
    s16x8 A1 = Abl[ct * 128 + 64];
    s16x8 Bh = *(const s16x8*)&cB[0][(ct * 4 + g) * 128 + cl * 8];
    s16x8 Bl = *(const s16x8*)&cB[1][(ct * 4 + g) * 128 + cl * 8];
    f32x4 W0 = *(const f32x4*)&w2s[ct * 32 + 8 * g];
    f32x4 W1 = *(const f32x4*)&w2s[ct * 32 + 8 * g + 4];

    f32x4 T0a = {0,0,0,0}, T1a = {0,0,0,0}, T0b = {0,0,0,0}, T1b = {0,0,0,0};
    __builtin_amdgcn_s_setprio(1);
    T0a = mfma16(A0, B1a, T0a); T0a = mfma16(A0, B2a, T0a);
    T1a = mfma16(A1, B1a, T1a); T1a = mfma16(A1, B2a, T1a);
    T0b = mfma16(A0, B1b, T0b); T0b = mfma16(A0, B2b, T0b);
    T1b = mfma16(A1, B1b, T1b); T1b = mfma16(A1, B2b, T1b);
    __builtin_amdgcn_s_setprio(0);

    s16x8 PAa = soft8(T0a, T1a, W0, W1, h2ka, ct, m2A, mbA);
    s16x8 PAb = soft8(T0b, T1b, W0, W1, h2kb, ct, m2B, mbB);
    __builtin_amdgcn_s_setprio(1);
    pva0 = mfma16(PAa, Bh, pva0); pva1 = mfma16(PAa, Bl, pva1); pvsA = mfma16(PAa, ONES, pvsA);
    pvb0 = mfma16(PAb, Bh, pvb0); pvb1 = mfma16(PAb, Bl, pvb1); pvsB = mfma16(PAb, ONES, pvsB);
    __builtin_amdgcn_s_setprio(0);
  }
  f32x4 pva = pva0 + pva1;
  f32x4 pvb = pvb0 + pvb1;

  // ---- reduce (min, 2nd-min) over the 4 lane-groups sharing each pixel ----
  #pragma unroll
  for (int off = 16; off < 64; off <<= 1) {
    float mo = __shfl_xor(m2A, off), mbo = __shfl_xor(mbA, off);
    mbA = fminf(fminf(mbA, mbo), fmaxf(m2A, mo));
    m2A = fminf(m2A, mo);
    float mo2 = __shfl_xor(m2B, off), mbo2 = __shfl_xor(mbB, off);
    mbB = fminf(fminf(mbB, mbo2), fmaxf(m2B, mo2));
    m2B = fminf(m2B, mo2);
  }
  int kaA = __float_as_int(m2A) & 511;
  int kaB = __float_as_int(m2B) & 511;
  bool trigA = (__int_as_float(__float_as_int(mbA) & 0xFFFFFE00) -
                __int_as_float(__float_as_int(m2A) & 0xFFFFFE00)) < 0.045f;  // 0.02*KAPPA + margin
  bool trigB = (__int_as_float(__float_as_int(mbB) & 0xFFFFFE00) -
                __int_as_float(__float_as_int(m2B) & 0xFFFFFE00)) < 0.045f;

  if (cl == 0) {
    #pragma unroll
    for (int r = 0; r < 4; ++r) {
      ssum[wv][g * 4 + r]      = pvsA[r];
      ssum[wv][16 + g * 4 + r] = pvsB[r];
    }
  }
  if (lane < 16) { bks[wv][lane] = kaA; bks[wv][16 + lane] = kaB; }

  // ---- rare exact rescan (np-exact chain + precise sqrt, first occurrence) ----
  unsigned long long mask = __ballot(lane < 16 && trigA) |
                            (__ballot(lane < 16 && trigB) << 16);
  while (mask) {
    int pl = __ffsll((long long)mask) - 1; mask &= mask - 1;
    float hh[16];
    #pragma unroll
    for (int d = 0; d < 16; ++d)
      hh[d] = z[((size_t)(bimg * CH + l * D + d)) * HW + yx0 + pw + pl];
    float h2x = h2s[pw + pl];
    float bm = 1e30f; int bkk = 0;
    for (int rnd = 0; rnd < 8; ++rnd) {
      int k = rnd * 64 + lane;
      const float* cr = codes + ((size_t)l * K + k) * D;
      float cross = 0.f;
      #pragma unroll
      for (int d = 0; d < 16; ++d) cross = fmaf(hh[d], cr[d], cross);
      float d2 = (h2x - 2.f * cross) + w2g[l * K + k];
      d2 = fmaxf(d2, 1e-12f);
      float dist = sqrtf(d2);
      if (dist < bm) { bm = dist; bkk = k; }
    }
    #pragma unroll
    for (int off = 1; off < 64; off <<= 1) {
      float bo = __shfl_xor(bm, off); int ko = __shfl_xor(bkk, off);
      if (bo < bm || (bo == bm && ko < bkk)) { bm = bo; bkk = ko; }
    }
    if (lane == 0) bks[wv][pl] = bkk;
  }

  // ---- epilogue ----
  __syncthreads();
  const int pg0 = bimg * HW + yx0;
  f32x4 svA = *(const f32x4*)&ssum[wv][g * 4];
  f32x4 svB = *(const f32x4*)&ssum[wv][16 + g * 4];
  #pragma unroll
  for (int r = 0; r < 4; ++r) {
    out[(size_t)(pg0 + pw + g * 4 + r) * CH + l * D + cl]      = pva[r] * __builtin_amdgcn_rcpf(svA[r]);
    out[(size_t)(pg0 + pw + 16 + g * 4 + r) * CH + l * D + cl] = pvb[r] * __builtin_amdgcn_rcpf(svB[r]);
  }
  int kkA = bks[wv][cl];
  int kkB = bks[wv][16 + cl];
  float4 cvA = *(const float4*)&codes[((size_t)l * K + kkA) * D + g * 4];
  float4 cvB = *(const float4*)&codes[((size_t)l * K + kkB) * D + g * 4];
  *(float4*)&out[(size_t)BHW * CH + (size_t)(pg0 + pw + cl) * CH + l * D + g * 4]      = cvA;
  *(float4*)&out[(size_t)BHW * CH + (size_t)(pg0 + pw + 16 + cl) * CH + l * D + g * 4] = cvB;
  if (lane < 16) {
    out[(size_t)2 * BHW * CH + (size_t)(pg0 + pw + cl) * L + l]      = (float)kkA;
    out[(size_t)2 * BHW * CH + (size_t)(pg0 + pw + 16 + cl) * L + l] = (float)kkB;
  }
}
} // namespace

extern "C" void kernel_launch(void* const* d_in, const int* in_sizes, int n_in,
                              void* d_out, int out_size, void* d_ws, size_t ws_size,
                              hipStream_t stream) {
  const float* z     = (const float*)d_in[0];
  const float* codes = (const float*)d_in[1];
  float* out         = (float*)d_out;
  unsigned short* cA = (unsigned short*)d_ws;
  float* w2g         = (float*)((char*)d_ws + WS_CA_BYTES);
  float* w2k         = (float*)((char*)d_ws + WS_W2K_OFF);

  repack<<<dim3(L * K / 256), 256, 0, stream>>>(codes, cA, w2g, w2k);
  dim3 grid(BHW / PPB, L);
  enc_mfma<<<grid, TPB, 0, stream>>>(z, codes, cA, w2g, w2k, out);
}